// Round 5
// baseline (744.435 us; speedup 1.0000x reference)
//
#include <hip/hip_runtime.h>
#include <hip/hip_cooperative_groups.h>

namespace cg = cooperative_groups;

#define NN 4096
#define NE 8192
#define NLG 32768
#define HCA 16384     // A hash capacity (<=8192 keys, lf .5)
#define HCL 65536     // L/U hash capacity (<=32768 keys, lf .5)
#define CAP 32        // row bucket capacity (Poisson(4) max << 32)

typedef unsigned int u32;
typedef unsigned short u16;
typedef __attribute__((ext_vector_type(4))) float f32x4;
typedef __attribute__((ext_vector_type(8))) short bf16x8;
typedef __attribute__((ext_vector_type(8))) unsigned short u16x8;
typedef __attribute__((ext_vector_type(4))) unsigned short u16x4;
typedef __attribute__((ext_vector_type(4))) unsigned int u32x4;

__device__ __forceinline__ float bf2f(u16 u) { return __uint_as_float(((u32)u) << 16); }
__device__ __forceinline__ u16 f2bf(float f) {
    u32 x = __float_as_uint(f);
    return (u16)((x + 0x7fffu + ((x >> 16) & 1u)) >> 16);  // RNE
}

struct G { const u16* Aa; int lda; const u16* WT; int K; const float* bias;
           u16* dst; u16* dst2; float* dstf; int ldd; int relu; int mb; };

struct MegaArgs {
    const float *x, *ex, *eal, *eau;
    const int *nei, *eil, *eiu;
    const float *nW0, *nb0, *nW1, *nb1, *fnW, *fnb;
    const float *eWl0, *eWu0, *eb0, *eWl1, *eWu1, *eb1, *feW, *feb;
    u32* zbase; u32 zw4;
    u32 *keysA, *keysL, *valsL, *keysU, *valsU;
    u32 *cntA, *cntL, *cntU;
    u32 *colA, *colL, *colU; float *wL, *wU;
    u16 *Zb1n, *Zb1e, *Zb2n, *Zb2e, *h2b, *e2b;
    u16 *nW0T, *nW1T, *eW1T, *eW2T, *fnWT, *feWT;
    float *nb0s, *nb1s;
    float *outn, *oute;
};

__device__ __forceinline__ void ht_insert(u32* keys, u32* vals, u32 mask, u32 slot, u32 eid) {
    u32 key = slot + 1u;
    u32 h = (slot * 2654435761u) & mask;
    for (;;) {
        u32 k = keys[h];
        if (k == key) { if (vals) atomicMax(&vals[h], eid + 1u); return; }
        if (k == 0u) {
            u32 old = atomicCAS(&keys[h], 0u, key);
            if (old == 0u || old == key) { if (vals) atomicMax(&vals[h], eid + 1u); return; }
            continue;
        }
        h = (h + 1u) & mask;
    }
}

__device__ __forceinline__ void wtr(const float* src, u16* dst, int i, int Kp, int Nw, int ld, int kofs) {
    int nn = i / Kp, k = i - nn * Kp;
    dst[(size_t)nn * ld + kofs + k] = f2bf(src[(size_t)k * Nw + nn]);
}

__device__ __forceinline__ void spmm_do(const u32* cnt, const u32* col, const float* wgt,
                                        const u16* src, u16* dst, int t, int shift, int ld) {
    int row = t >> shift, g = t & ((1 << shift) - 1);
    u32 jn = cnt[row]; if (jn > CAP) jn = CAP;
    const u32* cp = col + row * CAP;
    const float* wp = wgt ? wgt + row * CAP : nullptr;
    float acc[8] = {};
    const u16* srcg = src + g * 8;
    for (u32 j = 0; j < jn; ++j) {
        u32 v = cp[j];
        float wv = wp ? wp[j] : 1.0f;
        u16x8 xv = *(const u16x8*)(srcg + (size_t)v * ld);
#pragma unroll
        for (int e = 0; e < 8; ++e) acc[e] = fmaf(wv, bf2f(xv[e]), acc[e]);
    }
    u16x8 o;
#pragma unroll
    for (int e = 0; e < 8; ++e) o[e] = f2bf(acc[e]);
    *(u16x8*)(dst + (size_t)row * ld + g * 8) = o;
}

__device__ __forceinline__ void gemm_do(const G& g, int bx, int ny, int lane) {
    int m0 = bx * 16, n0 = ny * 64;
    int row = lane & 15, koff = (lane >> 4) * 8;
    f32x4 acc[4] = {};
    const u16* Ap = g.Aa + (size_t)(m0 + row) * g.lda + koff;
    const u16* Wp = g.WT + (size_t)(n0 + row) * g.K + koff;
    size_t ws = (size_t)16 * g.K;
    for (int k0 = 0; k0 < g.K; k0 += 32) {
        bf16x8 af = *(const bf16x8*)(Ap + k0);
#pragma unroll
        for (int nt = 0; nt < 4; ++nt) {
            bf16x8 bf = *(const bf16x8*)(Wp + nt * ws + k0);
            acc[nt] = __builtin_amdgcn_mfma_f32_16x16x32_bf16(af, bf, acc[nt], 0, 0, 0);
        }
    }
    int orow = m0 + (lane >> 4) * 4;
#pragma unroll
    for (int nt = 0; nt < 4; ++nt) {
        int col = n0 + nt * 16 + row;
        float bv = g.bias[col];
#pragma unroll
        for (int r = 0; r < 4; ++r) {
            float v = acc[nt][r] + bv;
            if (g.relu) v = fmaxf(v, 0.f);
            size_t o = (size_t)(orow + r) * g.ldd + col;
            if (g.dstf) { g.dstf[o] = v; }
            else { u16 q = f2bf(v); g.dst[o] = q; if (g.dst2) g.dst2[o] = q; }
        }
    }
}

__device__ __forceinline__ void gemm_phase(const G& g0, const G& g1, int ncols64, int wid, int nw, int lane) {
    int totMB = g0.mb + g1.mb;
    int tot = totMB * ncols64;
    for (int t = wid; t < tot; t += nw) {
        int ny = t / totMB, bx = t - ny * totMB;
        if (bx < g0.mb) gemm_do(g0, bx, ny, lane);
        else gemm_do(g1, bx - g0.mb, ny, lane);
    }
}

__global__ __launch_bounds__(256, 2) void mega_kernel(MegaArgs A) {
    cg::grid_group grid = cg::this_grid();
    const int gid = blockIdx.x * blockDim.x + threadIdx.x;
    const int gsz = gridDim.x * blockDim.x;
    const int lane = threadIdx.x & 63;
    const int wid = gid >> 6;
    const int nw = gsz >> 6;

    // ---- P0: zero hash/cnt region + all conversions/transposes/bias-sums ----
    {
        u32 B0 = A.zw4;
        u32 B1 = B0 + 65536, B2 = B1 + 65536, B3 = B2 + 65536;
        u32 B4 = B3 + 24576, B5 = B4 + 49152, B6 = B5 + 12288, B7 = B6 + 12288;
        u32 B8 = B7 + 49152, B9 = B8 + 49152, B10 = B9 + 8192, B11 = B10 + 8192;
        u32 B12 = B11 + 256;
        u32x4 z4 = {0u, 0u, 0u, 0u};
        for (u32 i = gid; i < B12; i += gsz) {
            if (i < B0) { ((u32x4*)A.zbase)[i] = z4; }
            else if (i < B1) {
                u32 t = i - B0; int r = t >> 4, c = t & 15;
                f32x4 v = *(const f32x4*)(A.x + (size_t)t * 4);
                u16x4 o;
#pragma unroll
                for (int e = 0; e < 4; ++e) o[e] = f2bf(v[e]);
                *(u16x4*)(A.Zb1n + (size_t)r * 192 + c * 4) = o;
            } else if (i < B3) {
                u32 t = (i < B2) ? i - B1 : i - B2;
                int kofs = (i < B2) ? 0 : 96;
                int r = t >> 3, c = t & 7;
                f32x4 v = *(const f32x4*)(A.ex + (size_t)t * 4);
                u16x4 o;
#pragma unroll
                for (int e = 0; e < 4; ++e) o[e] = f2bf(v[e]);
                *(u16x4*)(A.Zb1e + (size_t)r * 192 + kofs + c * 4) = o;
            }
            else if (i < B4)  wtr(A.nW0,  A.nW0T, i - B3, 192, 128, 192, 0);
            else if (i < B5)  wtr(A.nW1,  A.nW1T, i - B4, 384, 128, 384, 0);
            else if (i < B6)  wtr(A.eWl0, A.eW1T, i - B5,  96, 128, 192, 0);
            else if (i < B7)  wtr(A.eWu0, A.eW1T, i - B6,  96, 128, 192, 96);
            else if (i < B8)  wtr(A.eWl1, A.eW2T, i - B7, 384, 128, 768, 0);
            else if (i < B9)  wtr(A.eWu1, A.eW2T, i - B8, 384, 128, 768, 384);
            else if (i < B10) wtr(A.fnW,  A.fnWT, i - B9, 128,  64, 128, 0);
            else if (i < B11) wtr(A.feW,  A.feWT, i - B10, 128, 64, 128, 0);
            else {
                u32 t = i - B11;
                if (t < 128) { float s = 0.f; for (int k = 0; k < 3; ++k) s += A.nb0[k * 128 + t]; A.nb0s[t] = s; }
                else { t -= 128; float s = 0.f; for (int k = 0; k < 3; ++k) s += A.nb1[k * 128 + t]; A.nb1s[t] = s; }
            }
        }
    }
    grid.sync();

    // ---- P1: hash insert (dedup; last-occurrence wins for L/U) ----
    for (int i = gid; i < NE + 2 * NLG; i += gsz) {
        if (i < NE) {
            ht_insert(A.keysA, nullptr, HCA - 1, (u32)A.nei[i] * (u32)NN + (u32)A.nei[NE + i], 0u);
        } else if (i < NE + NLG) {
            int e = i - NE;
            ht_insert(A.keysL, A.valsL, HCL - 1, (u32)A.eil[e] * (u32)NE + (u32)A.eil[NLG + e], (u32)e);
        } else {
            int e = i - NE - NLG;
            ht_insert(A.keysU, A.valsU, HCL - 1, (u32)A.eiu[e] * (u32)NE + (u32)A.eiu[NLG + e], (u32)e);
        }
    }
    grid.sync();

    // ---- P2: bucket fill from hash slots ----
    for (int i = gid; i < HCA + 2 * HCL; i += gsz) {
        if (i < HCA) {
            u32 k = A.keysA[i];
            if (k) {
                u32 r = (k - 1u) >> 12, v = (k - 1u) & 4095u;
                u32 p = atomicAdd(&A.cntA[r], 1u);
                if (p < CAP) A.colA[r * CAP + p] = v;
            }
        } else if (i < HCA + HCL) {
            int h = i - HCA;
            u32 k = A.keysL[h];
            if (k) {
                u32 r = (k - 1u) >> 13, q = (k - 1u) & 8191u;
                u32 p = atomicAdd(&A.cntL[r], 1u);
                if (p < CAP) { A.colL[r * CAP + p] = q; A.wL[r * CAP + p] = A.eal[A.valsL[h] - 1u]; }
            }
        } else {
            int h = i - HCA - HCL;
            u32 k = A.keysU[h];
            if (k) {
                u32 r = (k - 1u) >> 13, q = (k - 1u) & 8191u;
                u32 p = atomicAdd(&A.cntU[r], 1u);
                if (p < CAP) { A.colU[r * CAP + p] = q; A.wU[r * CAP + p] = A.eau[A.valsU[h] - 1u]; }
            }
        }
    }
    grid.sync();

    // ---- P3/P4: layer-1 hops (node 64c shift3, edge 32c shift2) ----
    {
        const int nAi = NN << 3, nEi = NE << 2, tot = nAi + 2 * nEi;
        for (int i = gid; i < tot; i += gsz) {
            if (i < nAi)            spmm_do(A.cntA, A.colA, nullptr, A.Zb1n,      A.Zb1n + 64,  i, 3, 192);
            else if (i < nAi + nEi) spmm_do(A.cntL, A.colL, A.wL,    A.Zb1e,      A.Zb1e + 32,  i - nAi, 2, 192);
            else                    spmm_do(A.cntU, A.colU, A.wU,    A.Zb1e + 96, A.Zb1e + 128, i - nAi - nEi, 2, 192);
        }
        grid.sync();
        for (int i = gid; i < tot; i += gsz) {
            if (i < nAi)            spmm_do(A.cntA, A.colA, nullptr, A.Zb1n + 64,  A.Zb1n + 128, i, 3, 192);
            else if (i < nAi + nEi) spmm_do(A.cntL, A.colL, A.wL,    A.Zb1e + 32,  A.Zb1e + 64,  i - nAi, 2, 192);
            else                    spmm_do(A.cntU, A.colU, A.wU,    A.Zb1e + 128, A.Zb1e + 160, i - nAi - nEi, 2, 192);
        }
    }
    grid.sync();

    // ---- P5: layer-1 GEMMs ----
    {
        G g0{A.Zb1n, 192, A.nW0T, 192, A.nb0s, A.Zb2n, nullptr, nullptr, 384, 1, 256};
        G g1{A.Zb1e, 192, A.eW1T, 192, A.eb0,  A.Zb2e, A.Zb2e + 384, nullptr, 768, 1, 512};
        gemm_phase(g0, g1, 2, wid, nw, lane);
    }
    grid.sync();

    // ---- P6/P7: layer-2 hops (128c shift4) ----
    {
        const int nAi = NN << 4, nEi = NE << 4, tot = nAi + 2 * nEi;
        for (int i = gid; i < tot; i += gsz) {
            if (i < nAi)            spmm_do(A.cntA, A.colA, nullptr, A.Zb2n,       A.Zb2n + 128, i, 4, 384);
            else if (i < nAi + nEi) spmm_do(A.cntL, A.colL, A.wL,    A.Zb2e,       A.Zb2e + 128, i - nAi, 4, 768);
            else                    spmm_do(A.cntU, A.colU, A.wU,    A.Zb2e + 384, A.Zb2e + 512, i - nAi - nEi, 4, 768);
        }
        grid.sync();
        for (int i = gid; i < tot; i += gsz) {
            if (i < nAi)            spmm_do(A.cntA, A.colA, nullptr, A.Zb2n + 128, A.Zb2n + 256, i, 4, 384);
            else if (i < nAi + nEi) spmm_do(A.cntL, A.colL, A.wL,    A.Zb2e + 128, A.Zb2e + 256, i - nAi, 4, 768);
            else                    spmm_do(A.cntU, A.colU, A.wU,    A.Zb2e + 512, A.Zb2e + 640, i - nAi - nEi, 4, 768);
        }
    }
    grid.sync();

    // ---- P8: layer-2 GEMMs ----
    {
        G g0{A.Zb2n, 384, A.nW1T, 384, A.nb1s, A.h2b, nullptr, nullptr, 128, 1, 256};
        G g1{A.Zb2e, 768, A.eW2T, 768, A.eb1,  A.e2b, nullptr, nullptr, 128, 1, 512};
        gemm_phase(g0, g1, 2, wid, nw, lane);
    }
    grid.sync();

    // ---- P9: heads -> fp32 d_out ----
    {
        G g0{A.h2b, 128, A.fnWT, 128, A.fnb, nullptr, nullptr, A.outn, 64, 0, 256};
        G g1{A.e2b, 128, A.feWT, 128, A.feb, nullptr, nullptr, A.oute, 64, 0, 512};
        gemm_phase(g0, g1, 1, wid, nw, lane);
    }
}

// ---------------- launch ----------------
extern "C" void kernel_launch(void* const* d_in, const int* in_sizes, int n_in,
                              void* d_out, int out_size, void* d_ws, size_t ws_size,
                              hipStream_t stream)
{
    MegaArgs A;
    A.x    = (const float*)d_in[0];
    A.ex   = (const float*)d_in[1];
    A.nei  = (const int*)d_in[2];
    A.eil  = (const int*)d_in[3];
    A.eal  = (const float*)d_in[4];
    A.eiu  = (const int*)d_in[5];
    A.eau  = (const float*)d_in[6];
    A.nW0  = (const float*)d_in[7];
    A.nb0  = (const float*)d_in[8];
    A.nW1  = (const float*)d_in[9];
    A.nb1  = (const float*)d_in[10];
    A.fnW  = (const float*)d_in[11];
    A.fnb  = (const float*)d_in[12];
    A.eWl0 = (const float*)d_in[13];
    A.eWu0 = (const float*)d_in[14];
    A.eb0  = (const float*)d_in[15];
    A.eWl1 = (const float*)d_in[16];
    A.eWu1 = (const float*)d_in[17];
    A.eb1  = (const float*)d_in[18];
    A.feW  = (const float*)d_in[19];
    A.feb  = (const float*)d_in[20];

    char* wsb = (char*)d_ws;
    size_t off = 0;
    auto alloc = [&](size_t bytes) { void* p = wsb + off; off += (bytes + 255) & ~(size_t)255; return p; };

    // zeroed region (P0)
    A.keysA = (u32*)alloc(HCA * 4);
    A.keysL = (u32*)alloc(HCL * 4);
    A.valsL = (u32*)alloc(HCL * 4);
    A.keysU = (u32*)alloc(HCL * 4);
    A.valsU = (u32*)alloc(HCL * 4);
    A.cntA  = (u32*)alloc(NN * 4);
    A.cntL  = (u32*)alloc(NE * 4);
    A.cntU  = (u32*)alloc(NE * 4);
    size_t zbytes = off;
    A.zbase = (u32*)d_ws;
    A.zw4 = (u32)(zbytes / 16);

    A.colA = (u32*)alloc((size_t)NN * CAP * 4);
    A.colL = (u32*)alloc((size_t)NE * CAP * 4);
    A.colU = (u32*)alloc((size_t)NE * CAP * 4);
    A.wL   = (float*)alloc((size_t)NE * CAP * 4);
    A.wU   = (float*)alloc((size_t)NE * CAP * 4);

    A.Zb1n = (u16*)alloc((size_t)4096 * 192 * 2);
    A.Zb1e = (u16*)alloc((size_t)8192 * 192 * 2);
    A.Zb2n = (u16*)alloc((size_t)4096 * 384 * 2);
    A.Zb2e = (u16*)alloc((size_t)8192 * 768 * 2);
    A.h2b  = (u16*)alloc((size_t)4096 * 128 * 2);
    A.e2b  = (u16*)alloc((size_t)8192 * 128 * 2);

    A.nW0T = (u16*)alloc((size_t)128 * 192 * 2);
    A.nW1T = (u16*)alloc((size_t)128 * 384 * 2);
    A.eW1T = (u16*)alloc((size_t)128 * 192 * 2);
    A.eW2T = (u16*)alloc((size_t)128 * 768 * 2);
    A.fnWT = (u16*)alloc((size_t)64 * 128 * 2);
    A.feWT = (u16*)alloc((size_t)64 * 128 * 2);
    A.nb0s = (float*)alloc(128 * 4);
    A.nb1s = (float*)alloc(128 * 4);

    A.outn = (float*)d_out;
    A.oute = (float*)d_out + 262144;

    void* kargs[] = { &A };
    hipLaunchCooperativeKernel((void*)mega_kernel, dim3(512), dim3(256), kargs, 0, stream);
}

// Round 6
// 401.200 us; speedup vs baseline: 1.8555x; 1.8555x over previous
//
#include <hip/hip_runtime.h>

#define NN 4096
#define NE 8192
#define NLG 32768
#define CAP 32

typedef unsigned int u32;
typedef unsigned short u16;
typedef __attribute__((ext_vector_type(4))) float f32x4;
typedef __attribute__((ext_vector_type(8))) short bf16x8;
typedef __attribute__((ext_vector_type(8))) unsigned short u16x8;
typedef __attribute__((ext_vector_type(4))) unsigned short u16x4;
typedef __attribute__((ext_vector_type(4))) unsigned int u32x4;

__device__ __forceinline__ float bf2f(u16 u) { return __uint_as_float(((u32)u) << 16); }
__device__ __forceinline__ u16 f2bf(float f) {
    u32 x = __float_as_uint(f);
    return (u16)((x + 0x7fffu + ((x >> 16) & 1u)) >> 16);  // RNE
}

// ================= P0: zero counters + fp32->bf16 converts / transposes / bias sums =================
struct PrepArgs {
    const float *x, *ex, *nW0, *nb0, *nW1, *nb1, *fnW, *eWl0, *eWu0, *eWl1, *eWu1, *feW;
    u32* zbase; u32 zw4;
    u16 *Zb1n, *Zb1e, *nW0T, *nW1T, *eW1T, *eW2T, *fnWT, *feWT;
    float *nb0s, *nb1s;
};

__device__ __forceinline__ void wtr(const float* src, u16* dst, int i, int Kp, int Nw, int ld, int kofs) {
    int nn = i / Kp, k = i - nn * Kp;
    dst[(size_t)nn * ld + kofs + k] = f2bf(src[(size_t)k * Nw + nn]);
}

__global__ __launch_bounds__(256) void prep_kernel(PrepArgs A) {
    const u32 gid = blockIdx.x * blockDim.x + threadIdx.x;
    const u32 gsz = gridDim.x * blockDim.x;
    u32 B0 = A.zw4;
    u32 B1 = B0 + 65536, B2 = B1 + 65536, B3 = B2 + 65536;
    u32 B4 = B3 + 24576, B5 = B4 + 49152, B6 = B5 + 12288, B7 = B6 + 12288;
    u32 B8 = B7 + 49152, B9 = B8 + 49152, B10 = B9 + 8192, B11 = B10 + 8192;
    u32 B12 = B11 + 256;
    u32x4 z4 = {0u, 0u, 0u, 0u};
    for (u32 i = gid; i < B12; i += gsz) {
        if (i < B0) { ((u32x4*)A.zbase)[i] = z4; }
        else if (i < B1) {
            u32 t = i - B0; int r = t >> 4, c = t & 15;
            f32x4 v = *(const f32x4*)(A.x + (size_t)t * 4);
            u16x4 o;
#pragma unroll
            for (int e = 0; e < 4; ++e) o[e] = f2bf(v[e]);
            *(u16x4*)(A.Zb1n + (size_t)r * 192 + c * 4) = o;
        } else if (i < B3) {
            u32 t = (i < B2) ? i - B1 : i - B2;
            int kofs = (i < B2) ? 0 : 96;
            int r = t >> 3, c = t & 7;
            f32x4 v = *(const f32x4*)(A.ex + (size_t)t * 4);
            u16x4 o;
#pragma unroll
            for (int e = 0; e < 4; ++e) o[e] = f2bf(v[e]);
            *(u16x4*)(A.Zb1e + (size_t)r * 192 + kofs + c * 4) = o;
        }
        else if (i < B4)  wtr(A.nW0,  A.nW0T, i - B3, 192, 128, 192, 0);
        else if (i < B5)  wtr(A.nW1,  A.nW1T, i - B4, 384, 128, 384, 0);
        else if (i < B6)  wtr(A.eWl0, A.eW1T, i - B5,  96, 128, 192, 0);
        else if (i < B7)  wtr(A.eWu0, A.eW1T, i - B6,  96, 128, 192, 96);
        else if (i < B8)  wtr(A.eWl1, A.eW2T, i - B7, 384, 128, 768, 0);
        else if (i < B9)  wtr(A.eWu1, A.eW2T, i - B8, 384, 128, 768, 384);
        else if (i < B10) wtr(A.fnW,  A.fnWT, i - B9, 128,  64, 128, 0);
        else if (i < B11) wtr(A.feW,  A.feWT, i - B10, 128, 64, 128, 0);
        else {
            u32 t = i - B11;
            if (t < 128) { float s = 0.f; for (int k = 0; k < 3; ++k) s += A.nb0[k * 128 + t]; A.nb0s[t] = s; }
            else { t -= 128; float s = 0.f; for (int k = 0; k < 3; ++k) s += A.nb1[k * 128 + t]; A.nb1s[t] = s; }
        }
    }
}

// ================= P1: raw bucket append (no hash; dedup deferred to spmm) =================
struct AppArgs {
    const int *nei, *eil, *eiu;
    u32 *cntA, *cntL, *cntU;
    u32 *colA, *colL, *colU, *eidL, *eidU;
};

__global__ __launch_bounds__(256) void append_kernel(AppArgs A) {
    int id = blockIdx.x * blockDim.x + threadIdx.x;
    if (id < NE) {
        int r = A.nei[id];
        u32 p = atomicAdd(&A.cntA[r], 1u);
        if (p < CAP) A.colA[r * CAP + p] = (u32)A.nei[NE + id];
    } else if (id < NE + NLG) {
        int e = id - NE;
        int r = A.eil[e];
        u32 p = atomicAdd(&A.cntL[r], 1u);
        if (p < CAP) { A.colL[r * CAP + p] = (u32)A.eil[NLG + e]; A.eidL[r * CAP + p] = (u32)e; }
    } else if (id < NE + 2 * NLG) {
        int e = id - NE - NLG;
        int r = A.eiu[e];
        u32 p = atomicAdd(&A.cntU[r], 1u);
        if (p < CAP) { A.colU[r * CAP + p] = (u32)A.eiu[NLG + e]; A.eidU[r * CAP + p] = (u32)e; }
    }
}

// ================= 2-hop gather SpMM with inline dedup =================
// set-semantics dedup: weighted (L/U): winner = max eid among same col; binary (A): first occurrence.
struct SpM { const u32* cnt; const u32* col; const u32* eid; const float* attr; };
struct S2 { SpM M; const u16* src; u16* dst1; u16* dst2; int n; int shift; int ld; };

__device__ __forceinline__ void row_acc(const SpM& M, int row, const u16* srcg, int ld,
                                        float scale, float acc[8]) {
    u32 jn = M.cnt[row]; if (jn > CAP) jn = CAP;
    const u32* cp = M.col + row * CAP;
    if (M.attr) {
        const u32* ep = M.eid + row * CAP;
        for (u32 j = 0; j < jn; ++j) {
            u32 q = cp[j], e = ep[j];
            bool win = true;
            for (u32 j2 = 0; j2 < jn; ++j2)
                if (j2 != j && cp[j2] == q && ep[j2] > e) win = false;
            if (!win) continue;
            float w = scale * M.attr[e];
            u16x8 xv = *(const u16x8*)(srcg + (size_t)q * ld);
#pragma unroll
            for (int k = 0; k < 8; ++k) acc[k] = fmaf(w, bf2f(xv[k]), acc[k]);
        }
    } else {
        for (u32 j = 0; j < jn; ++j) {
            u32 v = cp[j];
            bool first = true;
            for (u32 j2 = 0; j2 < j; ++j2) if (cp[j2] == v) first = false;
            if (!first) continue;
            u16x8 xv = *(const u16x8*)(srcg + (size_t)v * ld);
#pragma unroll
            for (int k = 0; k < 8; ++k) acc[k] = fmaf(scale, bf2f(xv[k]), acc[k]);
        }
    }
}

__device__ __forceinline__ void two_hop(const S2& s, int t) {
    int row = t >> s.shift, g = t & ((1 << s.shift) - 1);
    const u16* srcg = s.src + g * 8;
    float a1[8] = {}, a2[8] = {};
    u32 jn = s.M.cnt[row]; if (jn > CAP) jn = CAP;
    const u32* cp = s.M.col + row * CAP;
    if (s.M.attr) {
        const u32* ep = s.M.eid + row * CAP;
        for (u32 j = 0; j < jn; ++j) {
            u32 q = cp[j], e = ep[j];
            bool win = true;
            for (u32 j2 = 0; j2 < jn; ++j2)
                if (j2 != j && cp[j2] == q && ep[j2] > e) win = false;
            if (!win) continue;
            float w = s.M.attr[e];
            u16x8 xv = *(const u16x8*)(srcg + (size_t)q * s.ld);
#pragma unroll
            for (int k = 0; k < 8; ++k) a1[k] = fmaf(w, bf2f(xv[k]), a1[k]);
            row_acc(s.M, q, srcg, s.ld, w, a2);
        }
    } else {
        for (u32 j = 0; j < jn; ++j) {
            u32 v = cp[j];
            bool first = true;
            for (u32 j2 = 0; j2 < j; ++j2) if (cp[j2] == v) first = false;
            if (!first) continue;
            u16x8 xv = *(const u16x8*)(srcg + (size_t)v * s.ld);
#pragma unroll
            for (int k = 0; k < 8; ++k) a1[k] += bf2f(xv[k]);
            row_acc(s.M, v, srcg, s.ld, 1.0f, a2);
        }
    }
    u16x8 o1, o2;
#pragma unroll
    for (int k = 0; k < 8; ++k) { o1[k] = f2bf(a1[k]); o2[k] = f2bf(a2[k]); }
    *(u16x8*)(s.dst1 + (size_t)row * s.ld + g * 8) = o1;
    *(u16x8*)(s.dst2 + (size_t)row * s.ld + g * 8) = o2;
}

__global__ __launch_bounds__(256) void spmm2hop(S2 a, S2 b, S2 c) {
    int id = blockIdx.x * blockDim.x + threadIdx.x;
    if (id < a.n) two_hop(a, id);
    else if (id < a.n + b.n) two_hop(b, id - a.n);
    else if (id < a.n + b.n + c.n) two_hop(c, id - a.n - b.n);
}

// ================= MFMA GEMM pieces =================
struct G { const u16* Aa; int lda; const u16* WT; int K; const float* bias;
           u16* dst; u16* dst2; int ldd; };

__device__ __forceinline__ void gemm_do(const G& g, int bx, int ny, int lane) {
    int m0 = bx * 16, n0 = ny * 64;
    int row = lane & 15, koff = (lane >> 4) * 8;
    f32x4 acc[4] = {};
    const u16* Ap = g.Aa + (size_t)(m0 + row) * g.lda + koff;
    const u16* Wp = g.WT + (size_t)(n0 + row) * g.K + koff;
    size_t ws = (size_t)16 * g.K;
    for (int k0 = 0; k0 < g.K; k0 += 32) {
        bf16x8 af = *(const bf16x8*)(Ap + k0);
#pragma unroll
        for (int nt = 0; nt < 4; ++nt) {
            bf16x8 bf = *(const bf16x8*)(Wp + nt * ws + k0);
            acc[nt] = __builtin_amdgcn_mfma_f32_16x16x32_bf16(af, bf, acc[nt], 0, 0, 0);
        }
    }
    int orow = m0 + (lane >> 4) * 4;
#pragma unroll
    for (int nt = 0; nt < 4; ++nt) {
        int col = n0 + nt * 16 + row;
        float bv = g.bias[col];
#pragma unroll
        for (int r = 0; r < 4; ++r) {
            float v = fmaxf(acc[nt][r] + bv, 0.f);  // relu
            size_t o = (size_t)(orow + r) * g.ldd + col;
            u16 q = f2bf(v); g.dst[o] = q; if (g.dst2) g.dst2[o] = q;
        }
    }
}

// layer-1 GEMMs: node (256 m-tiles) + edge (512 m-tiles), ny in {0,1}
__global__ __launch_bounds__(256) void gemm1_kernel(G g0, G g1) {
    int wv = threadIdx.x >> 6, lane = threadIdx.x & 63;
    int bxg = blockIdx.x * 4 + wv;
    int ny = blockIdx.y;
    if (bxg < 256) gemm_do(g0, bxg, ny, lane);
    else gemm_do(g1, bxg - 256, ny, lane);
}

// ================= fused layer-2 GEMM + output head =================
struct GHArgs {
    const u16 *Zb2n, *Zb2e, *nW1T, *eW2T, *fnWT, *feWT;
    const float *nb1s, *eb1, *fnb, *feb;
    float *outn, *oute;
};

__global__ __launch_bounds__(256) void gemm2_head(GHArgs A) {
    __shared__ u16 lds[4][16 * 128];
    int wv = threadIdx.x >> 6, lane = threadIdx.x & 63;
    int s = blockIdx.x * 4 + wv;
    int c = lane & 15, q = lane >> 4, koff = q * 8;
    const u16 *Ab, *WT, *hWT; const float *bias, *hB; float* outp; int lda, K, m0;
    if (s < 256) { Ab = A.Zb2n; lda = 384; K = 384; WT = A.nW1T; bias = A.nb1s;
                   hWT = A.fnWT; hB = A.fnb; outp = A.outn; m0 = s * 16; }
    else { int t = s - 256; Ab = A.Zb2e; lda = 768; K = 768; WT = A.eW2T; bias = A.eb1;
           hWT = A.feWT; hB = A.feb; outp = A.oute; m0 = t * 16; }
    u16* L = lds[wv];
    const u16* Ap = Ab + (size_t)(m0 + c) * lda + koff;
    for (int half = 0; half < 2; ++half) {
        f32x4 acc[4] = {};
        const u16* Wp = WT + (size_t)(half * 64 + c) * K + koff;
        size_t ws = (size_t)16 * K;
        for (int k0 = 0; k0 < K; k0 += 32) {
            bf16x8 af = *(const bf16x8*)(Ap + k0);
#pragma unroll
            for (int nt = 0; nt < 4; ++nt) {
                bf16x8 bf = *(const bf16x8*)(Wp + nt * ws + k0);
                acc[nt] = __builtin_amdgcn_mfma_f32_16x16x32_bf16(af, bf, acc[nt], 0, 0, 0);
            }
        }
#pragma unroll
        for (int nt = 0; nt < 4; ++nt) {
            int col = half * 64 + nt * 16 + c;
            float bv = bias[col];
#pragma unroll
            for (int r = 0; r < 4; ++r)
                L[(q * 4 + r) * 128 + col] = f2bf(fmaxf(acc[nt][r] + bv, 0.f));
        }
    }
    // head: 16x64 = relu-strip(16x128 in LDS) @ hWT^T + hB, fp32 out
    f32x4 hacc[4] = {};
    const u16* Hp = hWT + (size_t)c * 128 + koff;
#pragma unroll
    for (int k0 = 0; k0 < 128; k0 += 32) {
        bf16x8 af = *(const bf16x8*)(L + c * 128 + koff + k0);
#pragma unroll
        for (int nt = 0; nt < 4; ++nt) {
            bf16x8 bf = *(const bf16x8*)(Hp + nt * 16 * 128 + k0);
            hacc[nt] = __builtin_amdgcn_mfma_f32_16x16x32_bf16(af, bf, hacc[nt], 0, 0, 0);
        }
    }
#pragma unroll
    for (int nt = 0; nt < 4; ++nt) {
        int col = nt * 16 + c;
        float bv = hB[col];
#pragma unroll
        for (int r = 0; r < 4; ++r)
            outp[(size_t)(m0 + q * 4 + r) * 64 + col] = hacc[nt][r] + bv;
    }
}

// ================= launch =================
extern "C" void kernel_launch(void* const* d_in, const int* in_sizes, int n_in,
                              void* d_out, int out_size, void* d_ws, size_t ws_size,
                              hipStream_t stream)
{
    const float* x    = (const float*)d_in[0];
    const float* ex   = (const float*)d_in[1];
    const int*   nei  = (const int*)d_in[2];
    const int*   eil  = (const int*)d_in[3];
    const float* eal  = (const float*)d_in[4];
    const int*   eiu  = (const int*)d_in[5];
    const float* eau  = (const float*)d_in[6];
    const float* nW0  = (const float*)d_in[7];
    const float* nb0  = (const float*)d_in[8];
    const float* nW1  = (const float*)d_in[9];
    const float* nb1  = (const float*)d_in[10];
    const float* fnW  = (const float*)d_in[11];
    const float* fnb  = (const float*)d_in[12];
    const float* eWl0 = (const float*)d_in[13];
    const float* eWu0 = (const float*)d_in[14];
    const float* eb0  = (const float*)d_in[15];
    const float* eWl1 = (const float*)d_in[16];
    const float* eWu1 = (const float*)d_in[17];
    const float* eb1  = (const float*)d_in[18];
    const float* feW  = (const float*)d_in[19];
    const float* feb  = (const float*)d_in[20];

    char* wsb = (char*)d_ws;
    size_t off = 0;
    auto alloc = [&](size_t bytes) { void* p = wsb + off; off += (bytes + 255) & ~(size_t)255; return p; };

    // zeroed region (by prep P0): counters only
    u32* cntA = (u32*)alloc(NN * 4);
    u32* cntL = (u32*)alloc(NE * 4);
    u32* cntU = (u32*)alloc(NE * 4);
    size_t zbytes = off;

    u32* colA = (u32*)alloc((size_t)NN * CAP * 4);
    u32* colL = (u32*)alloc((size_t)NE * CAP * 4);
    u32* colU = (u32*)alloc((size_t)NE * CAP * 4);
    u32* eidL = (u32*)alloc((size_t)NE * CAP * 4);
    u32* eidU = (u32*)alloc((size_t)NE * CAP * 4);

    u16* Zb1n = (u16*)alloc((size_t)4096 * 192 * 2);
    u16* Zb1e = (u16*)alloc((size_t)8192 * 192 * 2);
    u16* Zb2n = (u16*)alloc((size_t)4096 * 384 * 2);
    u16* Zb2e = (u16*)alloc((size_t)8192 * 768 * 2);

    u16* nW0T = (u16*)alloc((size_t)128 * 192 * 2);
    u16* nW1T = (u16*)alloc((size_t)128 * 384 * 2);
    u16* eW1T = (u16*)alloc((size_t)128 * 192 * 2);
    u16* eW2T = (u16*)alloc((size_t)128 * 768 * 2);
    u16* fnWT = (u16*)alloc((size_t)64 * 128 * 2);
    u16* feWT = (u16*)alloc((size_t)64 * 128 * 2);
    float* nb0s = (float*)alloc(128 * 4);
    float* nb1s = (float*)alloc(128 * 4);

    // ---- P0: prep ----
    PrepArgs PA{x, ex, nW0, nb0, nW1, nb1, fnW, eWl0, eWu0, eWl1, eWu1, feW,
                (u32*)d_ws, (u32)(zbytes / 16),
                Zb1n, Zb1e, nW0T, nW1T, eW1T, eW2T, fnWT, feWT, nb0s, nb1s};
    prep_kernel<<<dim3(1024), dim3(256), 0, stream>>>(PA);

    // ---- P1: append ----
    AppArgs AA{nei, eil, eiu, cntA, cntL, cntU, colA, colL, colU, eidL, eidU};
    append_kernel<<<dim3((NE + 2 * NLG + 255) / 256), dim3(256), 0, stream>>>(AA);

    SpM MA{cntA, colA, nullptr, nullptr};
    SpM ML{cntL, colL, eidL, eal};
    SpM MU{cntU, colU, eidU, eau};

    // ---- P2: layer-1 2-hop spmm (node 8 col-groups, edge 4) ----
    {
        S2 sa{MA, Zb1n,      Zb1n + 64,  Zb1n + 128, NN << 3, 3, 192};
        S2 sb{ML, Zb1e,      Zb1e + 32,  Zb1e + 64,  NE << 2, 2, 192};
        S2 sc{MU, Zb1e + 96, Zb1e + 128, Zb1e + 160, NE << 2, 2, 192};
        int n = sa.n + sb.n + sc.n;
        spmm2hop<<<dim3((n + 255) / 256), dim3(256), 0, stream>>>(sa, sb, sc);
    }

    // ---- P3: layer-1 GEMMs ----
    {
        G g0{Zb1n, 192, nW0T, 192, nb0s, Zb2n, nullptr, 384};
        G g1{Zb1e, 192, eW1T, 192, eb0,  Zb2e, Zb2e + 384, 768};
        gemm1_kernel<<<dim3(192, 2), dim3(256), 0, stream>>>(g0, g1);
    }

    // ---- P4: layer-2 2-hop spmm (16 col-groups) ----
    {
        S2 sa{MA, Zb2n,       Zb2n + 128, Zb2n + 256, NN << 4, 4, 384};
        S2 sb{ML, Zb2e,       Zb2e + 128, Zb2e + 256, NE << 4, 4, 768};
        S2 sc{MU, Zb2e + 384, Zb2e + 512, Zb2e + 640, NE << 4, 4, 768};
        int n = sa.n + sb.n + sc.n;
        spmm2hop<<<dim3((n + 255) / 256), dim3(256), 0, stream>>>(sa, sb, sc);
    }

    // ---- P5: fused layer-2 GEMM + head ----
    GHArgs GH{Zb2n, Zb2e, nW1T, eW2T, fnWT, feWT,
              nb1s, eb1, fnb, feb,
              (float*)d_out, (float*)d_out + 262144};
    gemm2_head<<<dim3(192), dim3(256), 0, stream>>>(GH);
}

// Round 7
// 201.297 us; speedup vs baseline: 3.6982x; 1.9931x over previous
//
#include <hip/hip_runtime.h>

#define NN 4096
#define NE 8192
#define NLG 32768
#define CAP 32

typedef unsigned int u32;
typedef unsigned short u16;
typedef __attribute__((ext_vector_type(4))) float f32x4;
typedef __attribute__((ext_vector_type(8))) short bf16x8;
typedef __attribute__((ext_vector_type(8))) unsigned short u16x8;
typedef __attribute__((ext_vector_type(4))) unsigned short u16x4;
typedef __attribute__((ext_vector_type(4))) unsigned int u32x4;

__device__ __forceinline__ float bf2f(u16 u) { return __uint_as_float(((u32)u) << 16); }
__device__ __forceinline__ u16 f2bf(float f) {
    u32 x = __float_as_uint(f);
    return (u16)((x + 0x7fffu + ((x >> 16) & 1u)) >> 16);  // RNE
}

// ================= P0: zero counters + fp32->bf16 converts / transposes / bias sums =================
struct PrepArgs {
    const float *x, *ex, *nW0, *nb0, *nW1, *nb1, *fnW, *eWl0, *eWu0, *eWl1, *eWu1, *feW;
    u32* zbase; u32 zw4;
    u16 *Zb1n, *Zb1e, *nW0T, *nW1T, *eW1T, *eW2T, *fnWT, *feWT;
    float *nb0s, *nb1s;
};

__device__ __forceinline__ void wtr(const float* src, u16* dst, int i, int Kp, int Nw, int ld, int kofs) {
    int nn = i / Kp, k = i - nn * Kp;
    dst[(size_t)nn * ld + kofs + k] = f2bf(src[(size_t)k * Nw + nn]);
}

__global__ __launch_bounds__(256) void prep_kernel(PrepArgs A) {
    const u32 gid = blockIdx.x * blockDim.x + threadIdx.x;
    const u32 gsz = gridDim.x * blockDim.x;
    u32 B0 = A.zw4;
    u32 B1 = B0 + 65536, B2 = B1 + 65536, B3 = B2 + 65536;
    u32 B4 = B3 + 24576, B5 = B4 + 49152, B6 = B5 + 12288, B7 = B6 + 12288;
    u32 B8 = B7 + 49152, B9 = B8 + 49152, B10 = B9 + 8192, B11 = B10 + 8192;
    u32 B12 = B11 + 256;
    u32x4 z4 = {0u, 0u, 0u, 0u};
    for (u32 i = gid; i < B12; i += gsz) {
        if (i < B0) { ((u32x4*)A.zbase)[i] = z4; }
        else if (i < B1) {
            u32 t = i - B0; int r = t >> 4, c = t & 15;
            f32x4 v = *(const f32x4*)(A.x + (size_t)t * 4);
            u16x4 o;
#pragma unroll
            for (int e = 0; e < 4; ++e) o[e] = f2bf(v[e]);
            *(u16x4*)(A.Zb1n + (size_t)r * 192 + c * 4) = o;
        } else if (i < B3) {
            u32 t = (i < B2) ? i - B1 : i - B2;
            int kofs = (i < B2) ? 0 : 96;
            int r = t >> 3, c = t & 7;
            f32x4 v = *(const f32x4*)(A.ex + (size_t)t * 4);
            u16x4 o;
#pragma unroll
            for (int e = 0; e < 4; ++e) o[e] = f2bf(v[e]);
            *(u16x4*)(A.Zb1e + (size_t)r * 192 + kofs + c * 4) = o;
        }
        else if (i < B4)  wtr(A.nW0,  A.nW0T, i - B3, 192, 128, 192, 0);
        else if (i < B5)  wtr(A.nW1,  A.nW1T, i - B4, 384, 128, 384, 0);
        else if (i < B6)  wtr(A.eWl0, A.eW1T, i - B5,  96, 128, 192, 0);
        else if (i < B7)  wtr(A.eWu0, A.eW1T, i - B6,  96, 128, 192, 96);
        else if (i < B8)  wtr(A.eWl1, A.eW2T, i - B7, 384, 128, 768, 0);
        else if (i < B9)  wtr(A.eWu1, A.eW2T, i - B8, 384, 128, 768, 384);
        else if (i < B10) wtr(A.fnW,  A.fnWT, i - B9, 128,  64, 128, 0);
        else if (i < B11) wtr(A.feW,  A.feWT, i - B10, 128, 64, 128, 0);
        else {
            u32 t = i - B11;
            if (t < 128) { float s = 0.f; for (int k = 0; k < 3; ++k) s += A.nb0[k * 128 + t]; A.nb0s[t] = s; }
            else { t -= 128; float s = 0.f; for (int k = 0; k < 3; ++k) s += A.nb1[k * 128 + t]; A.nb1s[t] = s; }
        }
    }
}

// ================= P1: raw bucket append =================
struct AppArgs {
    const int *nei, *eil, *eiu;
    u32 *cntA, *cntL, *cntU;
    u32 *colA, *colL, *colU, *eidL, *eidU;
};

__global__ __launch_bounds__(256) void append_kernel(AppArgs A) {
    int id = blockIdx.x * blockDim.x + threadIdx.x;
    if (id < NE) {
        int r = A.nei[id];
        u32 p = atomicAdd(&A.cntA[r], 1u);
        if (p < CAP) A.colA[r * CAP + p] = (u32)A.nei[NE + id];
    } else if (id < NE + NLG) {
        int e = id - NE;
        int r = A.eil[e];
        u32 p = atomicAdd(&A.cntL[r], 1u);
        if (p < CAP) { A.colL[r * CAP + p] = (u32)A.eil[NLG + e]; A.eidL[r * CAP + p] = (u32)e; }
    } else if (id < NE + 2 * NLG) {
        int e = id - NE - NLG;
        int r = A.eiu[e];
        u32 p = atomicAdd(&A.cntU[r], 1u);
        if (p < CAP) { A.colU[r * CAP + p] = (u32)A.eiu[NLG + e]; A.eidU[r * CAP + p] = (u32)e; }
    }
}

// ================= P2: resolve buckets (dedup + weight gather + pad to x4) =================
// A: first-occurrence (binary). L/U: winner = max eid per col (jnp "last set wins").
struct ResArgs {
    u32 *cntA, *cntL, *cntU;
    const u32 *colA, *colL, *colU, *eidL, *eidU;
    const float *eal, *eau;
    uint2 *rbA, *rbL, *rbU;
};

__global__ __launch_bounds__(256) void resolve_kernel(ResArgs A) {
    int id = blockIdx.x * blockDim.x + threadIdx.x;
    if (id < NN) {
        int row = id;
        u32 jn = A.cntA[row]; if (jn > CAP) jn = CAP;
        const u32* cp = A.colA + row * CAP;
        uint2* out = A.rbA + row * CAP;
        u32 m = 0;
        for (u32 j = 0; j < jn; ++j) {
            u32 cj = cp[j];
            bool first = true;
            for (u32 j2 = 0; j2 < j; ++j2) if (cp[j2] == cj) first = false;
            if (first) { out[m] = make_uint2(cj, __float_as_uint(1.0f)); ++m; }
        }
        A.cntA[row] = m;
        for (u32 p = m; p < ((m + 3u) & ~3u); ++p) out[p] = make_uint2(0u, 0u);
    } else if (id < NN + 2 * NE) {
        bool isL = id < NN + NE;
        int row = isL ? (id - NN) : (id - NN - NE);
        u32* cnt = isL ? A.cntL : A.cntU;
        const u32* cp = (isL ? A.colL : A.colU) + row * CAP;
        const u32* ep = (isL ? A.eidL : A.eidU) + row * CAP;
        const float* attr = isL ? A.eal : A.eau;
        uint2* out = (isL ? A.rbL : A.rbU) + row * CAP;
        u32 jn = cnt[row]; if (jn > CAP) jn = CAP;
        u32 m = 0;
        for (u32 j = 0; j < jn; ++j) {
            u32 cj = cp[j], ej = ep[j];
            bool win = true;
            for (u32 j2 = 0; j2 < jn; ++j2)
                if (j2 != j && cp[j2] == cj && ep[j2] > ej) win = false;
            if (win) { out[m] = make_uint2(cj, __float_as_uint(attr[ej])); ++m; }
        }
        cnt[row] = m;
        for (u32 p = m; p < ((m + 3u) & ~3u); ++p) out[p] = make_uint2(0u, 0u);
    }
}

// ================= one-hop gather SpMM over resolved buckets =================
struct RSeg { const u32* cnt; const uint2* rb; const u16* src; u16* dst; int n; int shift; int ld; };

__device__ __forceinline__ void spmm_row8(const RSeg& s, int t) {
    int row = t >> s.shift, g = t & ((1 << s.shift) - 1);
    u32 jn = s.cnt[row];
    const uint2* bp = s.rb + (size_t)row * CAP;
    const u16* srcg = s.src + g * 8;
    float acc[8] = {};
    for (u32 j0 = 0; j0 < jn; j0 += 4) {
        uint2 q0 = bp[j0], q1 = bp[j0 + 1], q2 = bp[j0 + 2], q3 = bp[j0 + 3];
        u16x8 x0 = *(const u16x8*)(srcg + (size_t)q0.x * s.ld);
        u16x8 x1 = *(const u16x8*)(srcg + (size_t)q1.x * s.ld);
        u16x8 x2 = *(const u16x8*)(srcg + (size_t)q2.x * s.ld);
        u16x8 x3 = *(const u16x8*)(srcg + (size_t)q3.x * s.ld);
        float w0 = __uint_as_float(q0.y), w1 = __uint_as_float(q1.y);
        float w2 = __uint_as_float(q2.y), w3 = __uint_as_float(q3.y);
#pragma unroll
        for (int e = 0; e < 8; ++e) {
            acc[e] = fmaf(w0, bf2f(x0[e]), acc[e]);
            acc[e] = fmaf(w1, bf2f(x1[e]), acc[e]);
            acc[e] = fmaf(w2, bf2f(x2[e]), acc[e]);
            acc[e] = fmaf(w3, bf2f(x3[e]), acc[e]);
        }
    }
    u16x8 o;
#pragma unroll
    for (int e = 0; e < 8; ++e) o[e] = f2bf(acc[e]);
    *(u16x8*)(s.dst + (size_t)row * s.ld + g * 8) = o;
}

__device__ __forceinline__ void spmm_row4(const RSeg& s, int t) {
    int row = t >> s.shift, g = t & ((1 << s.shift) - 1);
    u32 jn = s.cnt[row];
    const uint2* bp = s.rb + (size_t)row * CAP;
    const u16* srcg = s.src + g * 4;
    float acc[4] = {};
    for (u32 j0 = 0; j0 < jn; j0 += 4) {
        uint2 q0 = bp[j0], q1 = bp[j0 + 1], q2 = bp[j0 + 2], q3 = bp[j0 + 3];
        u16x4 x0 = *(const u16x4*)(srcg + (size_t)q0.x * s.ld);
        u16x4 x1 = *(const u16x4*)(srcg + (size_t)q1.x * s.ld);
        u16x4 x2 = *(const u16x4*)(srcg + (size_t)q2.x * s.ld);
        u16x4 x3 = *(const u16x4*)(srcg + (size_t)q3.x * s.ld);
        float w0 = __uint_as_float(q0.y), w1 = __uint_as_float(q1.y);
        float w2 = __uint_as_float(q2.y), w3 = __uint_as_float(q3.y);
#pragma unroll
        for (int e = 0; e < 4; ++e) {
            acc[e] = fmaf(w0, bf2f(x0[e]), acc[e]);
            acc[e] = fmaf(w1, bf2f(x1[e]), acc[e]);
            acc[e] = fmaf(w2, bf2f(x2[e]), acc[e]);
            acc[e] = fmaf(w3, bf2f(x3[e]), acc[e]);
        }
    }
    u16x4 o;
#pragma unroll
    for (int e = 0; e < 4; ++e) o[e] = f2bf(acc[e]);
    *(u16x4*)(s.dst + (size_t)row * s.ld + g * 4) = o;
}

__global__ __launch_bounds__(256) void spmm8_kernel(RSeg a, RSeg b, RSeg c) {
    int id = blockIdx.x * blockDim.x + threadIdx.x;
    if (id < a.n) spmm_row8(a, id);
    else if (id < a.n + b.n) spmm_row8(b, id - a.n);
    else if (id < a.n + b.n + c.n) spmm_row8(c, id - a.n - b.n);
}

__global__ __launch_bounds__(256) void spmm4_kernel(RSeg a, RSeg b, RSeg c) {
    int id = blockIdx.x * blockDim.x + threadIdx.x;
    if (id < a.n) spmm_row4(a, id);
    else if (id < a.n + b.n) spmm_row4(b, id - a.n);
    else if (id < a.n + b.n + c.n) spmm_row4(c, id - a.n - b.n);
}

// ================= MFMA GEMM pieces =================
struct G { const u16* Aa; int lda; const u16* WT; int K; const float* bias;
           u16* dst; u16* dst2; int ldd; };

__device__ __forceinline__ void gemm_do(const G& g, int bx, int ny, int lane) {
    int m0 = bx * 16, n0 = ny * 64;
    int row = lane & 15, koff = (lane >> 4) * 8;
    f32x4 acc[4] = {};
    const u16* Ap = g.Aa + (size_t)(m0 + row) * g.lda + koff;
    const u16* Wp = g.WT + (size_t)(n0 + row) * g.K + koff;
    size_t ws = (size_t)16 * g.K;
    for (int k0 = 0; k0 < g.K; k0 += 32) {
        bf16x8 af = *(const bf16x8*)(Ap + k0);
#pragma unroll
        for (int nt = 0; nt < 4; ++nt) {
            bf16x8 bf = *(const bf16x8*)(Wp + nt * ws + k0);
            acc[nt] = __builtin_amdgcn_mfma_f32_16x16x32_bf16(af, bf, acc[nt], 0, 0, 0);
        }
    }
    int orow = m0 + (lane >> 4) * 4;
#pragma unroll
    for (int nt = 0; nt < 4; ++nt) {
        int col = n0 + nt * 16 + row;
        float bv = g.bias[col];
#pragma unroll
        for (int r = 0; r < 4; ++r) {
            float v = fmaxf(acc[nt][r] + bv, 0.f);  // relu
            size_t o = (size_t)(orow + r) * g.ldd + col;
            u16 q = f2bf(v); g.dst[o] = q; if (g.dst2) g.dst2[o] = q;
        }
    }
}

__global__ __launch_bounds__(256) void gemm1_kernel(G g0, G g1) {
    int wv = threadIdx.x >> 6, lane = threadIdx.x & 63;
    int bxg = blockIdx.x * 4 + wv;
    int ny = blockIdx.y;
    if (bxg < 256) gemm_do(g0, bxg, ny, lane);
    else gemm_do(g1, bxg - 256, ny, lane);
}

// ================= fused layer-2 GEMM + output head =================
struct GHArgs {
    const u16 *Zb2n, *Zb2e, *nW1T, *eW2T, *fnWT, *feWT;
    const float *nb1s, *eb1, *fnb, *feb;
    float *outn, *oute;
};

__global__ __launch_bounds__(256) void gemm2_head(GHArgs A) {
    __shared__ u16 lds[4][16 * 128];
    int wv = threadIdx.x >> 6, lane = threadIdx.x & 63;
    int s = blockIdx.x * 4 + wv;
    int c = lane & 15, q = lane >> 4, koff = q * 8;
    const u16 *Ab, *WT, *hWT; const float *bias, *hB; float* outp; int lda, K, m0;
    if (s < 256) { Ab = A.Zb2n; lda = 384; K = 384; WT = A.nW1T; bias = A.nb1s;
                   hWT = A.fnWT; hB = A.fnb; outp = A.outn; m0 = s * 16; }
    else { int t = s - 256; Ab = A.Zb2e; lda = 768; K = 768; WT = A.eW2T; bias = A.eb1;
           hWT = A.feWT; hB = A.feb; outp = A.oute; m0 = t * 16; }
    u16* L = lds[wv];
    const u16* Ap = Ab + (size_t)(m0 + c) * lda + koff;
    for (int half = 0; half < 2; ++half) {
        f32x4 acc[4] = {};
        const u16* Wp = WT + (size_t)(half * 64 + c) * K + koff;
        size_t ws = (size_t)16 * K;
        for (int k0 = 0; k0 < K; k0 += 32) {
            bf16x8 af = *(const bf16x8*)(Ap + k0);
#pragma unroll
            for (int nt = 0; nt < 4; ++nt) {
                bf16x8 bf = *(const bf16x8*)(Wp + nt * ws + k0);
                acc[nt] = __builtin_amdgcn_mfma_f32_16x16x32_bf16(af, bf, acc[nt], 0, 0, 0);
            }
        }
#pragma unroll
        for (int nt = 0; nt < 4; ++nt) {
            int col = half * 64 + nt * 16 + c;
            float bv = bias[col];
#pragma unroll
            for (int r = 0; r < 4; ++r)
                L[(q * 4 + r) * 128 + col] = f2bf(fmaxf(acc[nt][r] + bv, 0.f));
        }
    }
    f32x4 hacc[4] = {};
    const u16* Hp = hWT + (size_t)c * 128 + koff;
#pragma unroll
    for (int k0 = 0; k0 < 128; k0 += 32) {
        bf16x8 af = *(const bf16x8*)(L + c * 128 + koff + k0);
#pragma unroll
        for (int nt = 0; nt < 4; ++nt) {
            bf16x8 bf = *(const bf16x8*)(Hp + nt * 16 * 128 + k0);
            hacc[nt] = __builtin_amdgcn_mfma_f32_16x16x32_bf16(af, bf, hacc[nt], 0, 0, 0);
        }
    }
#pragma unroll
    for (int nt = 0; nt < 4; ++nt) {
        int col = nt * 16 + c;
        float bv = hB[col];
#pragma unroll
        for (int r = 0; r < 4; ++r)
            outp[(size_t)(m0 + q * 4 + r) * 64 + col] = hacc[nt][r] + bv;
    }
}

// ================= launch =================
extern "C" void kernel_launch(void* const* d_in, const int* in_sizes, int n_in,
                              void* d_out, int out_size, void* d_ws, size_t ws_size,
                              hipStream_t stream)
{
    const float* x    = (const float*)d_in[0];
    const float* ex   = (const float*)d_in[1];
    const int*   nei  = (const int*)d_in[2];
    const int*   eil  = (const int*)d_in[3];
    const float* eal  = (const float*)d_in[4];
    const int*   eiu  = (const int*)d_in[5];
    const float* eau  = (const float*)d_in[6];
    const float* nW0  = (const float*)d_in[7];
    const float* nb0  = (const float*)d_in[8];
    const float* nW1  = (const float*)d_in[9];
    const float* nb1  = (const float*)d_in[10];
    const float* fnW  = (const float*)d_in[11];
    const float* fnb  = (const float*)d_in[12];
    const float* eWl0 = (const float*)d_in[13];
    const float* eWu0 = (const float*)d_in[14];
    const float* eb0  = (const float*)d_in[15];
    const float* eWl1 = (const float*)d_in[16];
    const float* eWu1 = (const float*)d_in[17];
    const float* eb1  = (const float*)d_in[18];
    const float* feW  = (const float*)d_in[19];
    const float* feb  = (const float*)d_in[20];

    char* wsb = (char*)d_ws;
    size_t off = 0;
    auto alloc = [&](size_t bytes) { void* p = wsb + off; off += (bytes + 255) & ~(size_t)255; return p; };

    // zeroed region (by prep P0): counters only
    u32* cntA = (u32*)alloc(NN * 4);
    u32* cntL = (u32*)alloc(NE * 4);
    u32* cntU = (u32*)alloc(NE * 4);
    size_t zbytes = off;

    u32* colA = (u32*)alloc((size_t)NN * CAP * 4);
    u32* colL = (u32*)alloc((size_t)NE * CAP * 4);
    u32* colU = (u32*)alloc((size_t)NE * CAP * 4);
    u32* eidL = (u32*)alloc((size_t)NE * CAP * 4);
    u32* eidU = (u32*)alloc((size_t)NE * CAP * 4);
    uint2* rbA = (uint2*)alloc((size_t)NN * CAP * 8);
    uint2* rbL = (uint2*)alloc((size_t)NE * CAP * 8);
    uint2* rbU = (uint2*)alloc((size_t)NE * CAP * 8);

    u16* Zb1n = (u16*)alloc((size_t)4096 * 192 * 2);
    u16* Zb1e = (u16*)alloc((size_t)8192 * 192 * 2);
    u16* Zb2n = (u16*)alloc((size_t)4096 * 384 * 2);
    u16* Zb2e = (u16*)alloc((size_t)8192 * 768 * 2);

    u16* nW0T = (u16*)alloc((size_t)128 * 192 * 2);
    u16* nW1T = (u16*)alloc((size_t)128 * 384 * 2);
    u16* eW1T = (u16*)alloc((size_t)128 * 192 * 2);
    u16* eW2T = (u16*)alloc((size_t)128 * 768 * 2);
    u16* fnWT = (u16*)alloc((size_t)64 * 128 * 2);
    u16* feWT = (u16*)alloc((size_t)64 * 128 * 2);
    float* nb0s = (float*)alloc(128 * 4);
    float* nb1s = (float*)alloc(128 * 4);

    // ---- P0: prep ----
    PrepArgs PA{x, ex, nW0, nb0, nW1, nb1, fnW, eWl0, eWu0, eWl1, eWu1, feW,
                (u32*)d_ws, (u32)(zbytes / 16),
                Zb1n, Zb1e, nW0T, nW1T, eW1T, eW2T, fnWT, feWT, nb0s, nb1s};
    prep_kernel<<<dim3(1024), dim3(256), 0, stream>>>(PA);

    // ---- P1: append ----
    AppArgs AA{nei, eil, eiu, cntA, cntL, cntU, colA, colL, colU, eidL, eidU};
    append_kernel<<<dim3((NE + 2 * NLG + 255) / 256), dim3(256), 0, stream>>>(AA);

    // ---- P2: resolve ----
    ResArgs RA{cntA, cntL, cntU, colA, colL, colU, eidL, eidU, eal, eau, rbA, rbL, rbU};
    resolve_kernel<<<dim3((NN + 2 * NE + 255) / 256), dim3(256), 0, stream>>>(RA);

    auto launch_spmm8 = [&](RSeg a, RSeg b, RSeg c) {
        int n = a.n + b.n + c.n;
        spmm8_kernel<<<dim3((n + 255) / 256), dim3(256), 0, stream>>>(a, b, c);
    };
    auto launch_spmm4 = [&](RSeg a, RSeg b, RSeg c) {
        int n = a.n + b.n + c.n;
        spmm4_kernel<<<dim3((n + 255) / 256), dim3(256), 0, stream>>>(a, b, c);
    };

    // ---- P3/P4: layer-1 hops (width-4 groups: node 16 grps, edge 8 grps) ----
    launch_spmm4(RSeg{cntA, rbA, Zb1n,      Zb1n + 64,  NN << 4, 4, 192},
                 RSeg{cntL, rbL, Zb1e,      Zb1e + 32,  NE << 3, 3, 192},
                 RSeg{cntU, rbU, Zb1e + 96, Zb1e + 128, NE << 3, 3, 192});
    launch_spmm4(RSeg{cntA, rbA, Zb1n + 64,  Zb1n + 128, NN << 4, 4, 192},
                 RSeg{cntL, rbL, Zb1e + 32,  Zb1e + 64,  NE << 3, 3, 192},
                 RSeg{cntU, rbU, Zb1e + 128, Zb1e + 160, NE << 3, 3, 192});

    // ---- P5: layer-1 GEMMs ----
    {
        G g0{Zb1n, 192, nW0T, 192, nb0s, Zb2n, nullptr, 384};
        G g1{Zb1e, 192, eW1T, 192, eb0,  Zb2e, Zb2e + 384, 768};
        gemm1_kernel<<<dim3(192, 2), dim3(256), 0, stream>>>(g0, g1);
    }

    // ---- P6/P7: layer-2 hops (width-8 groups: 16 grps each) ----
    launch_spmm8(RSeg{cntA, rbA, Zb2n,       Zb2n + 128, NN << 4, 4, 384},
                 RSeg{cntL, rbL, Zb2e,       Zb2e + 128, NE << 4, 4, 768},
                 RSeg{cntU, rbU, Zb2e + 384, Zb2e + 512, NE << 4, 4, 768});
    launch_spmm8(RSeg{cntA, rbA, Zb2n + 128, Zb2n + 256, NN << 4, 4, 384},
                 RSeg{cntL, rbL, Zb2e + 128, Zb2e + 256, NE << 4, 4, 768},
                 RSeg{cntU, rbU, Zb2e + 512, Zb2e + 640, NE << 4, 4, 768});

    // ---- P8: fused layer-2 GEMM + head ----
    GHArgs GH{Zb2n, Zb2e, nW1T, eW2T, fnWT, feWT,
              nb1s, eb1, fnb, feb,
              (float*)d_out, (float*)d_out + 262144};
    gemm2_head<<<dim3(192), dim3(256), 0, stream>>>(GH);
}